// Round 1
// baseline (326.859 us; speedup 1.0000x reference)
//
#include <hip/hip_runtime.h>
#include <math.h>

#define IMG_H 2048
#define IMG_W 2048
#define TX 64
#define TY 32
#define HALO 3
#define TILE_H (TY + 2 * HALO)      // 38 halo rows
#define SIN_STR 76                  // dwords; 72 cols loaded + pad; verified conflict-free for b128
#define SHM_STR 68                  // dwords; 64 cols + pad; verified conflict-free for b128
#define CAND_CAP (1u << 20)
#define CBUF 1024
#define SEL_CAP 28672               // LDS staging capacity (112 KB) in final_select; ~27k expected

__device__ __forceinline__ float4 fmax4(float4 a, float4 b) {
    return make_float4(fmaxf(a.x, b.x), fmaxf(a.y, b.y), fmaxf(a.z, b.z), fmaxf(a.w, b.w));
}

typedef float __attribute__((ext_vector_type(4))) fvec4;
__device__ __forceinline__ void nt_store4(float* p, float4 v) {
    fvec4 w; w.x = v.x; w.y = v.y; w.z = v.z; w.w = v.w;
    __builtin_nontemporal_store(w, (fvec4*)p);
}

// Order-preserving float->uint key: ascending float order == ascending uint order.
__device__ __forceinline__ unsigned f2key(unsigned u) {
    unsigned mask = (unsigned)(((int)u >> 31)) | 0x80000000u;
    return u ^ mask;
}

// ctrl layout (16 u32 reserved, zeroed before launch):
// [0]=bucket [1]=rankInBucket [2]=cntA(window cands) [3]=ovf [5]=cntB(fallback) [7]=cntBelow
// medp lives at ctrl+8.
__device__ __forceinline__ bool is_covered(const unsigned* __restrict__ ctrl, unsigned k) {
    unsigned cb = ctrl[7];
    unsigned ca = ctrl[2]; if (ca > CAND_CAP) ca = CAND_CAP;
    return (ctrl[3] == 0u) && (k >= cb) && (k - cb < ca);
}

// Block-wide exclusive scan over 256 values (Hillis-Steele, 8 steps).
__device__ __forceinline__ unsigned block_exscan(unsigned val, unsigned* tmp) {
    const int t = threadIdx.x;
    tmp[t] = val;
    __syncthreads();
#pragma unroll
    for (int off = 1; off < 256; off <<= 1) {
        unsigned v = (t >= off) ? tmp[t - off] : 0u;
        __syncthreads();
        tmp[t] += v;
        __syncthreads();
    }
    return tmp[t] - val;
}

// Find bin b such that sum(bins[0..b)) <= k < sum(bins[0..b]). bins length = 256*C.
template <int C>
__device__ __forceinline__ void find_crossing(const unsigned* bins, unsigned k,
                                              unsigned* tmp, unsigned* res) {
    unsigned s = 0;
#pragma unroll
    for (int j = 0; j < C; ++j) s += bins[threadIdx.x * C + j];
    unsigned ex = block_exscan(s, tmp);
    if (k >= ex && k < ex + s) {  // exactly one thread
        unsigned cum = ex;
        int b = threadIdx.x * C;
        while (cum + bins[b] <= k) { cum += bins[b]; ++b; }
        res[0] = (unsigned)b;
        res[1] = k - cum;
    }
    __syncthreads();
}

// ---- Pass 1: count elements <= -W (register counter, no atomics in hot loop)
//      + compact window candidates (-W < x < W) to candA. Pure streaming read. ----
__global__ __launch_bounds__(256) void pass1_kernel(
        const float4* __restrict__ x, int n4, unsigned* __restrict__ ctrl,
        unsigned* __restrict__ candA, float W) {
    __shared__ unsigned cbuf[CBUF];
    __shared__ unsigned red[256];
    __shared__ unsigned ccnt, sbase, scnt;
    if (threadIdx.x == 0) ccnt = 0;
    __syncthreads();
    const float lo = -W, hi = W;
    unsigned cnt = 0;
    const int stride = gridDim.x * blockDim.x;
    for (int i = blockIdx.x * blockDim.x + threadIdx.x; i < n4; i += stride) {
        float4 v = x[i];
        cnt += (unsigned)(v.x <= lo) + (unsigned)(v.y <= lo) +
               (unsigned)(v.z <= lo) + (unsigned)(v.w <= lo);
        if (v.x > lo && v.x < hi) { unsigned p = atomicAdd(&ccnt, 1u); if (p < CBUF) cbuf[p] = f2key(__float_as_uint(v.x)); }
        if (v.y > lo && v.y < hi) { unsigned p = atomicAdd(&ccnt, 1u); if (p < CBUF) cbuf[p] = f2key(__float_as_uint(v.y)); }
        if (v.z > lo && v.z < hi) { unsigned p = atomicAdd(&ccnt, 1u); if (p < CBUF) cbuf[p] = f2key(__float_as_uint(v.z)); }
        if (v.w > lo && v.w < hi) { unsigned p = atomicAdd(&ccnt, 1u); if (p < CBUF) cbuf[p] = f2key(__float_as_uint(v.w)); }
    }
    // block-reduce the below-count, one global atomic per block
    red[threadIdx.x] = cnt;
    __syncthreads();
#pragma unroll
    for (int off = 128; off > 0; off >>= 1) {
        if (threadIdx.x < off) red[threadIdx.x] += red[threadIdx.x + off];
        __syncthreads();
    }
    if (threadIdx.x == 0) atomicAdd(&ctrl[7], red[0]);
    // flush candidates
    if (threadIdx.x == 0) {
        unsigned c = ccnt;
        if (c > CBUF) { c = CBUF; atomicOr(&ctrl[3], 1u); }          // LDS buffer overflow
        unsigned base = atomicAdd(&ctrl[2], c);
        if (base + c > CAND_CAP) {                                    // global buffer overflow
            atomicOr(&ctrl[3], 1u);
            c = base < CAND_CAP ? CAND_CAP - base : 0;
        }
        sbase = base; scnt = c;
    }
    __syncthreads();
    for (unsigned i = threadIdx.x; i < scnt; i += 256) candA[sbase + i] = cbuf[i];
}

// ---- Fallback: full 2048-bin histogram of top-11 key bits. Early-out when covered. ----
__global__ __launch_bounds__(256) void fallback_hist_kernel(
        const float4* __restrict__ x, int n4, unsigned* __restrict__ ghist,
        const unsigned* __restrict__ ctrl, unsigned k) {
    if (is_covered(ctrl, k)) return;   // uniform branch: launch-overhead only
    __shared__ unsigned h[4 * 2048];   // per-wave private histograms
    const int wave = threadIdx.x >> 6;
    unsigned* hw = &h[wave * 2048];
    for (int i = threadIdx.x; i < 4 * 2048; i += 256) h[i] = 0;
    __syncthreads();
    const int stride = gridDim.x * blockDim.x;
    for (int i = blockIdx.x * blockDim.x + threadIdx.x; i < n4; i += stride) {
        float4 v = x[i];
        atomicAdd(&hw[f2key(__float_as_uint(v.x)) >> 21], 1u);
        atomicAdd(&hw[f2key(__float_as_uint(v.y)) >> 21], 1u);
        atomicAdd(&hw[f2key(__float_as_uint(v.z)) >> 21], 1u);
        atomicAdd(&hw[f2key(__float_as_uint(v.w)) >> 21], 1u);
    }
    __syncthreads();
    for (int b = threadIdx.x; b < 2048; b += 256) {
        unsigned s = h[b] + h[2048 + b] + h[4096 + b] + h[6144 + b];
        if (s) atomicAdd(&ghist[b], s);
    }
}

// ---- Fallback: find bucket containing rank k. Early-out when covered. ----
__global__ __launch_bounds__(256) void find_bucket_kernel(
        const unsigned* __restrict__ ghist, unsigned k, unsigned* __restrict__ ctrl) {
    if (is_covered(ctrl, k)) return;
    __shared__ unsigned lh[2048];
    __shared__ unsigned tmp[256];
    __shared__ unsigned res[2];
    for (int i = threadIdx.x; i < 2048; i += 256) lh[i] = ghist[i];
    __syncthreads();
    find_crossing<8>(lh, k, tmp, res);
    if (threadIdx.x == 0) { ctrl[0] = res[0]; ctrl[1] = res[1]; }
}

// ---- Fallback: compact median-bucket keys from x. Early-out when covered. ----
__global__ __launch_bounds__(256) void compact_fallback_kernel(
        const float4* __restrict__ x, int n4, unsigned* __restrict__ ctrl,
        unsigned* __restrict__ candB, unsigned k) {
    if (is_covered(ctrl, k)) return;
    const unsigned bucket = ctrl[0];
    const int stride = gridDim.x * blockDim.x;
    for (int i = blockIdx.x * blockDim.x + threadIdx.x; i < n4; i += stride) {
        float4 v = x[i];
        unsigned ks[4] = { f2key(__float_as_uint(v.x)), f2key(__float_as_uint(v.y)),
                           f2key(__float_as_uint(v.z)), f2key(__float_as_uint(v.w)) };
#pragma unroll
        for (int j = 0; j < 4; ++j)
            if ((ks[j] >> 21) == bucket) {
                unsigned p = atomicAdd(&ctrl[5], 1u);
                if (p < CAND_CAP) candB[p] = ks[j];
            }
    }
}

// ---- Exact median. Covered path: rank (k - cntBelow) among candA via 3-level
//      radix select with LDS staging. Fallback path: old 2-level over candB. ----
__global__ __launch_bounds__(256) void final_select_kernel(
        unsigned* __restrict__ ctrl, const unsigned* __restrict__ candA,
        const unsigned* __restrict__ candB, float* __restrict__ medp, unsigned k) {
    __shared__ unsigned keys[SEL_CAP];   // 112 KB staging (single-block kernel)
    __shared__ unsigned h2[2048];
    __shared__ unsigned tmp[256];
    __shared__ unsigned res[2];
    const int t = threadIdx.x;
    if (is_covered(ctrl, k)) {
        unsigned M = ctrl[2];            // exact: no overflow on covered path
        const unsigned r = k - ctrl[7];
        const bool staged = (M <= SEL_CAP);
        if (staged) {
            unsigned M4 = M >> 2;
            const uint4* c4 = (const uint4*)candA;
            for (unsigned i = t; i < M4; i += 256) {
                uint4 q = c4[i];
                keys[4 * i] = q.x; keys[4 * i + 1] = q.y;
                keys[4 * i + 2] = q.z; keys[4 * i + 3] = q.w;
            }
            for (unsigned i = (M4 << 2) + t; i < M; i += 256) keys[i] = candA[i];
        }
        const unsigned* src = staged ? (const unsigned*)keys : candA;
        __syncthreads();
        // Level 1: key bits [31:21]
        for (unsigned i = t; i < 2048; i += 256) h2[i] = 0;
        __syncthreads();
        for (unsigned i = t; i < M; i += 256) atomicAdd(&h2[src[i] >> 21], 1u);
        __syncthreads();
        find_crossing<8>(h2, r, tmp, res);
        const unsigned b1 = res[0];
        const unsigned r1 = res[1];
        __syncthreads();
        // Level 2: key bits [20:10]
        for (unsigned i = t; i < 2048; i += 256) h2[i] = 0;
        __syncthreads();
        for (unsigned i = t; i < M; i += 256) {
            unsigned key = src[i];
            if ((key >> 21) == b1) atomicAdd(&h2[(key >> 10) & 0x7FFu], 1u);
        }
        __syncthreads();
        find_crossing<8>(h2, r1, tmp, res);
        const unsigned pref = (b1 << 11) | res[0];
        const unsigned r2 = res[1];
        __syncthreads();
        // Level 3: key bits [9:0]
        for (unsigned i = t; i < 1024; i += 256) h2[i] = 0;
        __syncthreads();
        for (unsigned i = t; i < M; i += 256) {
            unsigned key = src[i];
            if ((key >> 10) == pref) atomicAdd(&h2[key & 0x3FFu], 1u);
        }
        __syncthreads();
        find_crossing<4>(h2, r2, tmp, res);
        if (t == 0) {
            unsigned key = (pref << 10) | res[0];
            unsigned u = (key & 0x80000000u) ? (key ^ 0x80000000u) : ~key;
            *medp = __uint_as_float(u);
        }
    } else {
        unsigned M = ctrl[5]; if (M > CAND_CAP) M = CAND_CAP;
        const unsigned bucket = ctrl[0];
        const unsigned r = ctrl[1];
        // Level 2: key bits [20:10]
        for (int i = t; i < 2048; i += 256) h2[i] = 0;
        __syncthreads();
        for (unsigned i = t; i < M; i += 256) {
            unsigned key = candB[i];
            if ((key >> 21) == bucket) atomicAdd(&h2[(key >> 10) & 0x7FFu], 1u);
        }
        __syncthreads();
        find_crossing<8>(h2, r, tmp, res);
        const unsigned pref = (bucket << 11) | res[0];
        const unsigned r2 = res[1];
        __syncthreads();
        // Level 3: key bits [9:0]
        for (int i = t; i < 1024; i += 256) h2[i] = 0;
        __syncthreads();
        for (unsigned i = t; i < M; i += 256) {
            unsigned key = candB[i];
            if ((key >> 10) == pref) atomicAdd(&h2[key & 0x3FFu], 1u);
        }
        __syncthreads();
        find_crossing<4>(h2, r2, tmp, res);
        if (t == 0) {
            unsigned key = (pref << 10) | res[0];
            unsigned u = (key & 0x80000000u) ? (key ^ 0x80000000u) : ~key;
            *medp = __uint_as_float(u);
        }
    }
}

// ---- Fused threshold + 7x7 maxpool + NMS: all-b128 LDS, bank-optimal strides ----
// (Round-4 structure: horizontal-first separable max. Verified conflict-free:
//  every wave b128 access pattern hits each bank exactly 8 times. The
//  vertical-first variant is structurally 4-way conflicted — do not switch back.)
// Output stores are nontemporal: keeps x resident in L3 for this kernel's reads.
__global__ __launch_bounds__(256, 6) void nms_kernel(const float* __restrict__ x,
                                                     float* __restrict__ out,
                                                     const float* __restrict__ medp) {
    __shared__ __align__(16) float sin_[TILE_H * SIN_STR];  // 38x76 dwords = 11.5 KB
    __shared__ __align__(16) float shm[TILE_H * SHM_STR];   // 38x68 dwords = 10.3 KB
    const float med = *medp;
    const int tx0 = blockIdx.x * TX;
    const int ty0 = blockIdx.y * TY;
    const size_t ib = (size_t)blockIdx.z * (size_t)(IMG_H * IMG_W);
    const float* img = x + ib;
    float* oimg = out + ib;
    const bool colsafe = (tx0 >= 4) && (tx0 + 68 <= IMG_W);

    // Phase 1: load 38x72 halo tile as float4, threshold on the fly.
    for (int task = threadIdx.x; task < TILE_H * 18; task += 256) {
        int rr = task / 18;
        int c4 = task - rr * 18;
        int gy = ty0 + rr - HALO;
        int gx0 = tx0 - 4 + c4 * 4;
        float4 v;
        if ((unsigned)gy < (unsigned)IMG_H) {
            if (colsafe) {
                v = *(const float4*)(img + (size_t)gy * IMG_W + gx0);
                v.x = (v.x > med) ? v.x : 0.0f;
                v.y = (v.y > med) ? v.y : 0.0f;
                v.z = (v.z > med) ? v.z : 0.0f;
                v.w = (v.w > med) ? v.w : 0.0f;
            } else {
                float c[4];
#pragma unroll
                for (int j = 0; j < 4; ++j) {
                    int gx = gx0 + j;
                    if ((unsigned)gx < (unsigned)IMG_W) {
                        float xv = img[(size_t)gy * IMG_W + gx];
                        c[j] = (xv > med) ? xv : 0.0f;
                    } else c[j] = -INFINITY;
                }
                v = make_float4(c[0], c[1], c[2], c[3]);
            }
        } else {
            v = make_float4(-INFINITY, -INFINITY, -INFINITY, -INFINITY);
        }
        *(float4*)&sin_[rr * SIN_STR + c4 * 4] = v;
    }
    __syncthreads();

    // Phase 2: horizontal 7-tap max. 38 rows x 4 segments of 16 outputs.
    for (int task = threadIdx.x; task < TILE_H * 4; task += 256) {
        int rr = task >> 2;
        int s = task & 3;
        int c0 = s * 16;
        const float* p = &sin_[rr * SIN_STR + c0];
        float v[24];
#pragma unroll
        for (int b = 0; b < 6; ++b) {
            float4 q = *(const float4*)(p + 4 * b);
            v[4 * b] = q.x; v[4 * b + 1] = q.y; v[4 * b + 2] = q.z; v[4 * b + 3] = q.w;
        }
        float m2[22];
#pragma unroll
        for (int j = 1; j <= 21; ++j) m2[j] = fmaxf(v[j], v[j + 1]);
        float m4[20];
#pragma unroll
        for (int j = 1; j <= 19; ++j) m4[j] = fmaxf(m2[j], m2[j + 2]);
        float o[16];
#pragma unroll
        for (int j = 0; j < 16; ++j) o[j] = fmaxf(m4[j + 1], m4[j + 4]);  // max sin[j+1..j+7]
        float* q = &shm[rr * SHM_STR + c0];
#pragma unroll
        for (int b = 0; b < 4; ++b)
            *(float4*)(q + 4 * b) = make_float4(o[4 * b], o[4 * b + 1], o[4 * b + 2], o[4 * b + 3]);
    }
    __syncthreads();

    // Phase 3: vertical 7-tap max on float4 columns + NMS compare + float4 nt stores.
    {
        const int col4 = threadIdx.x & 15;
        const int r0 = (threadIdx.x >> 4) * 2;
        float4 v[8];
#pragma unroll
        for (int j = 0; j < 8; ++j) v[j] = *(const float4*)&shm[(r0 + j) * SHM_STR + col4 * 4];
        float4 m2[7];
#pragma unroll
        for (int j = 0; j < 7; ++j) m2[j] = fmax4(v[j], v[j + 1]);
        float4 m4[5];
#pragma unroll
        for (int j = 0; j < 5; ++j) m4[j] = fmax4(m2[j], m2[j + 2]);
        float4 ma = fmax4(m4[0], m4[3]);  // rows r0..r0+6   -> out row r0
        float4 mb = fmax4(m4[1], m4[4]);  // rows r0+1..r0+7 -> out row r0+1
        float4 ta = *(const float4*)&sin_[(r0 + HALO) * SIN_STR + col4 * 4 + 4];
        float4 tb = *(const float4*)&sin_[(r0 + 1 + HALO) * SIN_STR + col4 * 4 + 4];
        float4 oa = make_float4((ta.x == ma.x) ? ta.x : 0.0f, (ta.y == ma.y) ? ta.y : 0.0f,
                                (ta.z == ma.z) ? ta.z : 0.0f, (ta.w == ma.w) ? ta.w : 0.0f);
        float4 ob = make_float4((tb.x == mb.x) ? tb.x : 0.0f, (tb.y == mb.y) ? tb.y : 0.0f,
                                (tb.z == mb.z) ? tb.z : 0.0f, (tb.w == mb.w) ? tb.w : 0.0f);
        nt_store4(oimg + (size_t)(ty0 + r0) * IMG_W + tx0 + col4 * 4, oa);
        nt_store4(oimg + (size_t)(ty0 + r0 + 1) * IMG_W + tx0 + col4 * 4, ob);
    }
}

extern "C" void kernel_launch(void* const* d_in, const int* in_sizes, int n_in,
                              void* d_out, int out_size, void* d_ws, size_t ws_size,
                              hipStream_t stream) {
    const float* x = (const float*)d_in[0];
    float* out = (float*)d_out;
    const int n = in_sizes[0];                   // 8*2048*2048
    const int n4 = n / 4;
    const unsigned k = (unsigned)((n - 1) / 2);  // lower-median rank (0-indexed)

    unsigned char* ws = (unsigned char*)d_ws;
    unsigned* ghist = (unsigned*)ws;               // 2048 u32
    unsigned* ctrl = (unsigned*)(ws + 2048 * 4);   // 16 u32, see layout comment
    float* medp = (float*)(ctrl + 8);
    unsigned* candA = (unsigned*)(ws + 2048 * 4 + 64);
    unsigned* candB = candA + CAND_CAP;
    const size_t reserved = 2048 * 4 + 64;

    // ws is re-poisoned to 0xAA before every timed launch: zero hist + control words.
    hipMemsetAsync(d_ws, 0, reserved, stream);

    // Window around the expected median of ~N(0,1): |x| < 0.001 (~4.6 sigma of the
    // sample-median distribution at n=33.5M). Coverage is verified EXACTLY via
    // countBelow/cntA; the fallback chain handles arbitrary inputs (early-outs
    // to launch-overhead-only stubs when the window covers rank k).
    const float W = 0.001f;

    pass1_kernel<<<1024, 256, 0, stream>>>((const float4*)x, n4, ctrl, candA, W);
    fallback_hist_kernel<<<1024, 256, 0, stream>>>((const float4*)x, n4, ghist, ctrl, k);
    find_bucket_kernel<<<1, 256, 0, stream>>>(ghist, k, ctrl);
    compact_fallback_kernel<<<1024, 256, 0, stream>>>((const float4*)x, n4, ctrl, candB, k);
    final_select_kernel<<<1, 256, 0, stream>>>(ctrl, candA, candB, medp, k);

    dim3 grid(IMG_W / TX, IMG_H / TY, n / (IMG_H * IMG_W));
    nms_kernel<<<grid, 256, 0, stream>>>(x, out, medp);
}

// Round 2
// 325.908 us; speedup vs baseline: 1.0029x; 1.0029x over previous
//
#include <hip/hip_runtime.h>
#include <math.h>

#define IMG_H 2048
#define IMG_W 2048
#define TX 64
#define TY 32
#define HALO 3
#define TILE_H (TY + 2 * HALO)      // 38 halo rows
#define SIN_STR 76                  // dwords; 72 cols loaded + pad; verified conflict-free for b128
#define SHM_STR 68                  // dwords; 64 cols + pad; verified conflict-free for b128
#define CAND_CAP (1u << 20)
#define CBUF 1024
#define SEL_CAP 28672               // LDS staging capacity in final_select; ~27k expected at W=0.001
#define CSEL 4096                   // bin-compaction capacity (16 KB); expected ~13 members/bin

__device__ __forceinline__ float4 fmax4(float4 a, float4 b) {
    return make_float4(fmaxf(a.x, b.x), fmaxf(a.y, b.y), fmaxf(a.z, b.z), fmaxf(a.w, b.w));
}

// Order-preserving float->uint key: ascending float order == ascending uint order.
__device__ __forceinline__ unsigned f2key(unsigned u) {
    unsigned mask = (unsigned)(((int)u >> 31)) | 0x80000000u;
    return u ^ mask;
}
static inline unsigned f2key_host(float f) {
    union { float f; unsigned u; } c; c.f = f;
    unsigned mask = (unsigned)(((int)c.u >> 31)) | 0x80000000u;
    return c.u ^ mask;
}

// key -> float (inverse of f2key)
__device__ __forceinline__ float key2f(unsigned key) {
    unsigned u = (key & 0x80000000u) ? (key ^ 0x80000000u) : ~key;
    return __uint_as_float(u);
}

// Linear 2048-bin quantization of a window candidate (float strictly in (-W, W)).
// Monotone in key order: float add/mul by positive + trunc + clamp are all monotone.
// Near-uniform occupancy for locally-flat densities -> no same-address LDS atomic pileup.
__device__ __forceinline__ unsigned linbin(unsigned key, float W, float scale) {
    float p = (key2f(key) + W) * scale;
    int b = (int)p;
    b = b < 0 ? 0 : (b > 2047 ? 2047 : b);
    return (unsigned)b;
}

// ctrl layout (16 u32 reserved, zeroed before launch):
// [0]=bucket [1]=rankInBucket [2]=cntA(window cands) [3]=ovf [5]=cntB(fallback) [7]=cntBelow
// medp lives at ctrl+8.
__device__ __forceinline__ bool is_covered(const unsigned* __restrict__ ctrl, unsigned k) {
    unsigned cb = ctrl[7];
    unsigned ca = ctrl[2]; if (ca > CAND_CAP) ca = CAND_CAP;
    return (ctrl[3] == 0u) && (k >= cb) && (k - cb < ca);
}

// Block-wide exclusive scan over 256 values (Hillis-Steele, 8 steps).
__device__ __forceinline__ unsigned block_exscan(unsigned val, unsigned* tmp) {
    const int t = threadIdx.x;
    tmp[t] = val;
    __syncthreads();
#pragma unroll
    for (int off = 1; off < 256; off <<= 1) {
        unsigned v = (t >= off) ? tmp[t - off] : 0u;
        __syncthreads();
        tmp[t] += v;
        __syncthreads();
    }
    return tmp[t] - val;
}

// Find bin b such that sum(bins[0..b)) <= k < sum(bins[0..b]). bins length = 256*C.
template <int C>
__device__ __forceinline__ void find_crossing(const unsigned* bins, unsigned k,
                                              unsigned* tmp, unsigned* res) {
    unsigned s = 0;
#pragma unroll
    for (int j = 0; j < C; ++j) s += bins[threadIdx.x * C + j];
    unsigned ex = block_exscan(s, tmp);
    if (k >= ex && k < ex + s) {  // exactly one thread
        unsigned cum = ex;
        int b = threadIdx.x * C;
        while (cum + bins[b] <= k) { cum += bins[b]; ++b; }
        res[0] = (unsigned)b;
        res[1] = k - cum;
    }
    __syncthreads();
}

// ---- Pass 1: count keys <= keyLo (register counter, no hot-loop atomics)
//      + compact window candidates (keyLo < key < keyHi) to candA. Streaming read.
//      Key-space compares: exactly consistent with sort order for all bit patterns. ----
__global__ __launch_bounds__(256) void pass1_kernel(
        const float4* __restrict__ x, int n4, unsigned* __restrict__ ctrl,
        unsigned* __restrict__ candA, unsigned keyLo, unsigned keyHi) {
    __shared__ unsigned cbuf[CBUF];
    __shared__ unsigned red[256];
    __shared__ unsigned ccnt, sbase, scnt;
    if (threadIdx.x == 0) ccnt = 0;
    __syncthreads();
    unsigned cnt = 0;
    const int stride = gridDim.x * blockDim.x;
    for (int i = blockIdx.x * blockDim.x + threadIdx.x; i < n4; i += stride) {
        float4 v = x[i];
        unsigned k0 = f2key(__float_as_uint(v.x));
        unsigned k1 = f2key(__float_as_uint(v.y));
        unsigned k2 = f2key(__float_as_uint(v.z));
        unsigned k3 = f2key(__float_as_uint(v.w));
        cnt += (unsigned)(k0 <= keyLo) + (unsigned)(k1 <= keyLo) +
               (unsigned)(k2 <= keyLo) + (unsigned)(k3 <= keyLo);
        if (k0 > keyLo && k0 < keyHi) { unsigned p = atomicAdd(&ccnt, 1u); if (p < CBUF) cbuf[p] = k0; }
        if (k1 > keyLo && k1 < keyHi) { unsigned p = atomicAdd(&ccnt, 1u); if (p < CBUF) cbuf[p] = k1; }
        if (k2 > keyLo && k2 < keyHi) { unsigned p = atomicAdd(&ccnt, 1u); if (p < CBUF) cbuf[p] = k2; }
        if (k3 > keyLo && k3 < keyHi) { unsigned p = atomicAdd(&ccnt, 1u); if (p < CBUF) cbuf[p] = k3; }
    }
    // block-reduce the below-count, one global atomic per block
    red[threadIdx.x] = cnt;
    __syncthreads();
#pragma unroll
    for (int off = 128; off > 0; off >>= 1) {
        if (threadIdx.x < off) red[threadIdx.x] += red[threadIdx.x + off];
        __syncthreads();
    }
    if (threadIdx.x == 0) atomicAdd(&ctrl[7], red[0]);
    // flush candidates
    if (threadIdx.x == 0) {
        unsigned c = ccnt;
        if (c > CBUF) { c = CBUF; atomicOr(&ctrl[3], 1u); }          // LDS buffer overflow
        unsigned base = atomicAdd(&ctrl[2], c);
        if (base + c > CAND_CAP) {                                    // global buffer overflow
            atomicOr(&ctrl[3], 1u);
            c = base < CAND_CAP ? CAND_CAP - base : 0;
        }
        sbase = base; scnt = c;
    }
    __syncthreads();
    for (unsigned i = threadIdx.x; i < scnt; i += 256) candA[sbase + i] = cbuf[i];
}

// ---- Fallback: full 2048-bin histogram of top-11 key bits. Early-out when covered. ----
__global__ __launch_bounds__(256) void fallback_hist_kernel(
        const float4* __restrict__ x, int n4, unsigned* __restrict__ ghist,
        const unsigned* __restrict__ ctrl, unsigned k) {
    if (is_covered(ctrl, k)) return;   // uniform branch: launch-overhead only
    __shared__ unsigned h[4 * 2048];   // per-wave private histograms
    const int wave = threadIdx.x >> 6;
    unsigned* hw = &h[wave * 2048];
    for (int i = threadIdx.x; i < 4 * 2048; i += 256) h[i] = 0;
    __syncthreads();
    const int stride = gridDim.x * blockDim.x;
    for (int i = blockIdx.x * blockDim.x + threadIdx.x; i < n4; i += stride) {
        float4 v = x[i];
        atomicAdd(&hw[f2key(__float_as_uint(v.x)) >> 21], 1u);
        atomicAdd(&hw[f2key(__float_as_uint(v.y)) >> 21], 1u);
        atomicAdd(&hw[f2key(__float_as_uint(v.z)) >> 21], 1u);
        atomicAdd(&hw[f2key(__float_as_uint(v.w)) >> 21], 1u);
    }
    __syncthreads();
    for (int b = threadIdx.x; b < 2048; b += 256) {
        unsigned s = h[b] + h[2048 + b] + h[4096 + b] + h[6144 + b];
        if (s) atomicAdd(&ghist[b], s);
    }
}

// ---- Fallback: find bucket containing rank k. Early-out when covered. ----
__global__ __launch_bounds__(256) void find_bucket_kernel(
        const unsigned* __restrict__ ghist, unsigned k, unsigned* __restrict__ ctrl) {
    if (is_covered(ctrl, k)) return;
    __shared__ unsigned lh[2048];
    __shared__ unsigned tmp[256];
    __shared__ unsigned res[2];
    for (int i = threadIdx.x; i < 2048; i += 256) lh[i] = ghist[i];
    __syncthreads();
    find_crossing<8>(lh, k, tmp, res);
    if (threadIdx.x == 0) { ctrl[0] = res[0]; ctrl[1] = res[1]; }
}

// ---- Fallback: compact median-bucket keys from x. Early-out when covered. ----
__global__ __launch_bounds__(256) void compact_fallback_kernel(
        const float4* __restrict__ x, int n4, unsigned* __restrict__ ctrl,
        unsigned* __restrict__ candB, unsigned k) {
    if (is_covered(ctrl, k)) return;
    const unsigned bucket = ctrl[0];
    const int stride = gridDim.x * blockDim.x;
    for (int i = blockIdx.x * blockDim.x + threadIdx.x; i < n4; i += stride) {
        float4 v = x[i];
        unsigned ks[4] = { f2key(__float_as_uint(v.x)), f2key(__float_as_uint(v.y)),
                           f2key(__float_as_uint(v.z)), f2key(__float_as_uint(v.w)) };
#pragma unroll
        for (int j = 0; j < 4; ++j)
            if ((ks[j] >> 21) == bucket) {
                unsigned p = atomicAdd(&ctrl[5], 1u);
                if (p < CAND_CAP) candB[p] = ks[j];
            }
    }
}

// ---- Exact median. Covered path: rank (k - cntBelow) among candA.
//      Level 0: LINEAR 2048-bin quantization (uniform for locally-flat density ->
//      no same-address LDS-atomic serialization, unlike key-exponent bits which
//      concentrate ~27k candidates into ~16 bins). Then compact the chosen bin
//      (~13 members) and finish with an exact tie-correct rank-count.
//      Pathological bins (>CSEL members) fall to an exact key-bit 3-level select. ----
__global__ __launch_bounds__(256) void final_select_kernel(
        unsigned* __restrict__ ctrl, const unsigned* __restrict__ candA,
        const unsigned* __restrict__ candB, float* __restrict__ medp,
        unsigned k, float W) {
    __shared__ unsigned keys[SEL_CAP];   // 112 KB staging (single-block kernel)
    __shared__ unsigned cbin[CSEL];      // 16 KB chosen-bin compaction
    __shared__ unsigned h2[2048];
    __shared__ unsigned tmp[256];
    __shared__ unsigned res[2];
    __shared__ unsigned csize;
    const int t = threadIdx.x;
    if (is_covered(ctrl, k)) {
        unsigned M = ctrl[2];            // exact: no overflow on covered path
        const unsigned r = k - ctrl[7];
        const bool staged = (M <= SEL_CAP);
        if (staged) {
            unsigned M4 = M >> 2;
            const uint4* c4 = (const uint4*)candA;
            for (unsigned i = t; i < M4; i += 256) {
                uint4 q = c4[i];
                keys[4 * i] = q.x; keys[4 * i + 1] = q.y;
                keys[4 * i + 2] = q.z; keys[4 * i + 3] = q.w;
            }
            for (unsigned i = (M4 << 2) + t; i < M; i += 256) keys[i] = candA[i];
        }
        const unsigned* src = staged ? (const unsigned*)keys : candA;
        if (t == 0) csize = 0;
        const float scale = 1024.0f / W;   // 2048 bins over (-W, W)
        // Level 0: linear-bin histogram
        for (unsigned i = t; i < 2048; i += 256) h2[i] = 0;
        __syncthreads();
        for (unsigned i = t; i < M; i += 256) atomicAdd(&h2[linbin(src[i], W, scale)], 1u);
        __syncthreads();
        find_crossing<8>(h2, r, tmp, res);
        const unsigned b0 = res[0];
        const unsigned r0 = res[1];
        __syncthreads();
        // Compact chosen-bin members
        for (unsigned i = t; i < M; i += 256) {
            unsigned key = src[i];
            if (linbin(key, W, scale) == b0) {
                unsigned p = atomicAdd(&csize, 1u);
                if (p < CSEL) cbin[p] = key;
            }
        }
        __syncthreads();
        const unsigned C = csize;
        if (C <= CSEL) {
            // Exact rank-count: key K is the r0-th smallest iff
            // #{keys < K} <= r0 < #{keys <= K}. Duplicate writers write same value.
            for (unsigned i = t; i < C; i += 256) {
                unsigned key = cbin[i];
                unsigned less = 0, eq = 0;
                for (unsigned j = 0; j < C; ++j) {
                    unsigned kj = cbin[j];   // broadcast read, conflict-free
                    less += (unsigned)(kj < key);
                    eq += (unsigned)(kj == key);
                }
                if (less <= r0 && r0 < less + eq) res[0] = key;
            }
            __syncthreads();
            if (t == 0) *medp = key2f(res[0]);
        } else {
            // Adversarial concentration: exact 3-level key-bit select within bin b0.
            for (unsigned i = t; i < 2048; i += 256) h2[i] = 0;
            __syncthreads();
            for (unsigned i = t; i < M; i += 256) {
                unsigned key = src[i];
                if (linbin(key, W, scale) == b0) atomicAdd(&h2[key >> 21], 1u);
            }
            __syncthreads();
            find_crossing<8>(h2, r0, tmp, res);
            const unsigned b1 = res[0];
            const unsigned r1 = res[1];
            __syncthreads();
            for (unsigned i = t; i < 2048; i += 256) h2[i] = 0;
            __syncthreads();
            for (unsigned i = t; i < M; i += 256) {
                unsigned key = src[i];
                if (linbin(key, W, scale) == b0 && (key >> 21) == b1)
                    atomicAdd(&h2[(key >> 10) & 0x7FFu], 1u);
            }
            __syncthreads();
            find_crossing<8>(h2, r1, tmp, res);
            const unsigned pref = (b1 << 11) | res[0];
            const unsigned r2 = res[1];
            __syncthreads();
            for (unsigned i = t; i < 1024; i += 256) h2[i] = 0;
            __syncthreads();
            for (unsigned i = t; i < M; i += 256) {
                unsigned key = src[i];
                if (linbin(key, W, scale) == b0 && (key >> 10) == pref)
                    atomicAdd(&h2[key & 0x3FFu], 1u);
            }
            __syncthreads();
            find_crossing<4>(h2, r2, tmp, res);
            if (t == 0) *medp = key2f((pref << 10) | res[0]);
        }
    } else {
        unsigned M = ctrl[5]; if (M > CAND_CAP) M = CAND_CAP;
        const unsigned bucket = ctrl[0];
        const unsigned r = ctrl[1];
        // Level 2: key bits [20:10]
        for (int i = t; i < 2048; i += 256) h2[i] = 0;
        __syncthreads();
        for (unsigned i = t; i < M; i += 256) {
            unsigned key = candB[i];
            if ((key >> 21) == bucket) atomicAdd(&h2[(key >> 10) & 0x7FFu], 1u);
        }
        __syncthreads();
        find_crossing<8>(h2, r, tmp, res);
        const unsigned pref = (bucket << 11) | res[0];
        const unsigned r2 = res[1];
        __syncthreads();
        // Level 3: key bits [9:0]
        for (int i = t; i < 1024; i += 256) h2[i] = 0;
        __syncthreads();
        for (unsigned i = t; i < M; i += 256) {
            unsigned key = candB[i];
            if ((key >> 10) == pref) atomicAdd(&h2[key & 0x3FFu], 1u);
        }
        __syncthreads();
        find_crossing<4>(h2, r2, tmp, res);
        if (t == 0) *medp = key2f((pref << 10) | res[0]);
    }
}

// ---- Fused threshold + 7x7 maxpool + NMS: all-b128 LDS, bank-optimal strides ----
// (Horizontal-first separable max. Verified conflict-free: every wave b128 access
//  pattern hits each bank exactly 8 times. Vertical-first is structurally 4-way
//  conflicted — do not switch back.)
// Stores are REGULAR (not nontemporal): nt forced the 134 MB output to drain to
// HBM inside the kernel window (+~14 µs); regular stores retire into L2/L3 and
// write-back lazily. Verified by round-1 regression.
__global__ __launch_bounds__(256, 6) void nms_kernel(const float* __restrict__ x,
                                                     float* __restrict__ out,
                                                     const float* __restrict__ medp) {
    __shared__ __align__(16) float sin_[TILE_H * SIN_STR];  // 38x76 dwords = 11.5 KB
    __shared__ __align__(16) float shm[TILE_H * SHM_STR];   // 38x68 dwords = 10.3 KB
    const float med = *medp;
    const int tx0 = blockIdx.x * TX;
    const int ty0 = blockIdx.y * TY;
    const size_t ib = (size_t)blockIdx.z * (size_t)(IMG_H * IMG_W);
    const float* img = x + ib;
    float* oimg = out + ib;
    const bool colsafe = (tx0 >= 4) && (tx0 + 68 <= IMG_W);

    // Phase 1: load 38x72 halo tile as float4, threshold on the fly.
    for (int task = threadIdx.x; task < TILE_H * 18; task += 256) {
        int rr = task / 18;
        int c4 = task - rr * 18;
        int gy = ty0 + rr - HALO;
        int gx0 = tx0 - 4 + c4 * 4;
        float4 v;
        if ((unsigned)gy < (unsigned)IMG_H) {
            if (colsafe) {
                v = *(const float4*)(img + (size_t)gy * IMG_W + gx0);
                v.x = (v.x > med) ? v.x : 0.0f;
                v.y = (v.y > med) ? v.y : 0.0f;
                v.z = (v.z > med) ? v.z : 0.0f;
                v.w = (v.w > med) ? v.w : 0.0f;
            } else {
                float c[4];
#pragma unroll
                for (int j = 0; j < 4; ++j) {
                    int gx = gx0 + j;
                    if ((unsigned)gx < (unsigned)IMG_W) {
                        float xv = img[(size_t)gy * IMG_W + gx];
                        c[j] = (xv > med) ? xv : 0.0f;
                    } else c[j] = -INFINITY;
                }
                v = make_float4(c[0], c[1], c[2], c[3]);
            }
        } else {
            v = make_float4(-INFINITY, -INFINITY, -INFINITY, -INFINITY);
        }
        *(float4*)&sin_[rr * SIN_STR + c4 * 4] = v;
    }
    __syncthreads();

    // Phase 2: horizontal 7-tap max. 38 rows x 4 segments of 16 outputs.
    for (int task = threadIdx.x; task < TILE_H * 4; task += 256) {
        int rr = task >> 2;
        int s = task & 3;
        int c0 = s * 16;
        const float* p = &sin_[rr * SIN_STR + c0];
        float v[24];
#pragma unroll
        for (int b = 0; b < 6; ++b) {
            float4 q = *(const float4*)(p + 4 * b);
            v[4 * b] = q.x; v[4 * b + 1] = q.y; v[4 * b + 2] = q.z; v[4 * b + 3] = q.w;
        }
        float m2[22];
#pragma unroll
        for (int j = 1; j <= 21; ++j) m2[j] = fmaxf(v[j], v[j + 1]);
        float m4[20];
#pragma unroll
        for (int j = 1; j <= 19; ++j) m4[j] = fmaxf(m2[j], m2[j + 2]);
        float o[16];
#pragma unroll
        for (int j = 0; j < 16; ++j) o[j] = fmaxf(m4[j + 1], m4[j + 4]);  // max sin[j+1..j+7]
        float* q = &shm[rr * SHM_STR + c0];
#pragma unroll
        for (int b = 0; b < 4; ++b)
            *(float4*)(q + 4 * b) = make_float4(o[4 * b], o[4 * b + 1], o[4 * b + 2], o[4 * b + 3]);
    }
    __syncthreads();

    // Phase 3: vertical 7-tap max on float4 columns + NMS compare + float4 stores.
    {
        const int col4 = threadIdx.x & 15;
        const int r0 = (threadIdx.x >> 4) * 2;
        float4 v[8];
#pragma unroll
        for (int j = 0; j < 8; ++j) v[j] = *(const float4*)&shm[(r0 + j) * SHM_STR + col4 * 4];
        float4 m2[7];
#pragma unroll
        for (int j = 0; j < 7; ++j) m2[j] = fmax4(v[j], v[j + 1]);
        float4 m4[5];
#pragma unroll
        for (int j = 0; j < 5; ++j) m4[j] = fmax4(m2[j], m2[j + 2]);
        float4 ma = fmax4(m4[0], m4[3]);  // rows r0..r0+6   -> out row r0
        float4 mb = fmax4(m4[1], m4[4]);  // rows r0+1..r0+7 -> out row r0+1
        float4 ta = *(const float4*)&sin_[(r0 + HALO) * SIN_STR + col4 * 4 + 4];
        float4 tb = *(const float4*)&sin_[(r0 + 1 + HALO) * SIN_STR + col4 * 4 + 4];
        float4 oa = make_float4((ta.x == ma.x) ? ta.x : 0.0f, (ta.y == ma.y) ? ta.y : 0.0f,
                                (ta.z == ma.z) ? ta.z : 0.0f, (ta.w == ma.w) ? ta.w : 0.0f);
        float4 ob = make_float4((tb.x == mb.x) ? tb.x : 0.0f, (tb.y == mb.y) ? tb.y : 0.0f,
                                (tb.z == mb.z) ? tb.z : 0.0f, (tb.w == mb.w) ? tb.w : 0.0f);
        *(float4*)(oimg + (size_t)(ty0 + r0) * IMG_W + tx0 + col4 * 4) = oa;
        *(float4*)(oimg + (size_t)(ty0 + r0 + 1) * IMG_W + tx0 + col4 * 4) = ob;
    }
}

extern "C" void kernel_launch(void* const* d_in, const int* in_sizes, int n_in,
                              void* d_out, int out_size, void* d_ws, size_t ws_size,
                              hipStream_t stream) {
    const float* x = (const float*)d_in[0];
    float* out = (float*)d_out;
    const int n = in_sizes[0];                   // 8*2048*2048
    const int n4 = n / 4;
    const unsigned k = (unsigned)((n - 1) / 2);  // lower-median rank (0-indexed)

    unsigned char* ws = (unsigned char*)d_ws;
    unsigned* ghist = (unsigned*)ws;               // 2048 u32
    unsigned* ctrl = (unsigned*)(ws + 2048 * 4);   // 16 u32, see layout comment
    float* medp = (float*)(ctrl + 8);
    unsigned* candA = (unsigned*)(ws + 2048 * 4 + 64);
    unsigned* candB = candA + CAND_CAP;
    const size_t reserved = 2048 * 4 + 64;

    // ws is re-poisoned to 0xAA before every timed launch: zero hist + control words.
    hipMemsetAsync(d_ws, 0, reserved, stream);

    // Window around the expected median of ~N(0,1): |x| < 0.001 (~4.6 sigma of the
    // sample-median distribution at n=33.5M). Coverage is verified EXACTLY in key
    // space via countBelow/cntA; the fallback chain handles arbitrary inputs
    // (early-outs to launch-overhead-only stubs when the window covers rank k).
    const float W = 0.001f;
    const unsigned keyLo = f2key_host(-W);
    const unsigned keyHi = f2key_host(W);

    pass1_kernel<<<1024, 256, 0, stream>>>((const float4*)x, n4, ctrl, candA, keyLo, keyHi);
    fallback_hist_kernel<<<1024, 256, 0, stream>>>((const float4*)x, n4, ghist, ctrl, k);
    find_bucket_kernel<<<1, 256, 0, stream>>>(ghist, k, ctrl);
    compact_fallback_kernel<<<1024, 256, 0, stream>>>((const float4*)x, n4, ctrl, candB, k);
    final_select_kernel<<<1, 256, 0, stream>>>(ctrl, candA, candB, medp, k, W);

    dim3 grid(IMG_W / TX, IMG_H / TY, n / (IMG_H * IMG_W));
    nms_kernel<<<grid, 256, 0, stream>>>(x, out, medp);
}

// Round 3
// 312.740 us; speedup vs baseline: 1.0451x; 1.0421x over previous
//
#include <hip/hip_runtime.h>
#include <math.h>

#define IMG_H 2048
#define IMG_W 2048
#define TX 64
#define TY 32
#define HALO 3
#define TILE_H (TY + 2 * HALO)      // 38 halo rows
#define SIN_STR 76                  // dwords; 72 cols loaded + pad; verified conflict-free for b128
#define SHM_STR 68                  // dwords; 64 cols + pad; verified conflict-free for b128
#define CAND_CAP (1u << 20)
#define CBUF 1024
#define CSEL 4096                   // bin-compaction capacity (16 KB); expected ~13 members/bin

__device__ __forceinline__ float4 fmax4(float4 a, float4 b) {
    return make_float4(fmaxf(a.x, b.x), fmaxf(a.y, b.y), fmaxf(a.z, b.z), fmaxf(a.w, b.w));
}

// Order-preserving float->uint key: ascending float order == ascending uint order.
__device__ __forceinline__ unsigned f2key(unsigned u) {
    unsigned mask = (unsigned)(((int)u >> 31)) | 0x80000000u;
    return u ^ mask;
}
static inline unsigned f2key_host(float f) {
    union { float f; unsigned u; } c; c.f = f;
    unsigned mask = (unsigned)(((int)c.u >> 31)) | 0x80000000u;
    return c.u ^ mask;
}

// key -> float (inverse of f2key)
__device__ __forceinline__ float key2f(unsigned key) {
    unsigned u = (key & 0x80000000u) ? (key ^ 0x80000000u) : ~key;
    return __uint_as_float(u);
}

// Linear 2048-bin quantization of a window candidate (float strictly in (-W, W)).
// Monotone in key order; near-uniform occupancy for locally-flat densities ->
// no same-address LDS-atomic serialization (key-exponent bits would concentrate
// ~27k candidates into ~16 bins).
__device__ __forceinline__ unsigned linbin(unsigned key, float W, float scale) {
    float p = (key2f(key) + W) * scale;
    int b = (int)p;
    b = b < 0 ? 0 : (b > 2047 ? 2047 : b);
    return (unsigned)b;
}

// ctrl layout (16 u32 reserved, zeroed before launch):
// [0..1] unused [2]=cntA(window cands) [3]=ovf [7]=cntBelow ; medp at ctrl+8.
__device__ __forceinline__ bool is_covered(const unsigned* __restrict__ ctrl, unsigned k) {
    unsigned cb = ctrl[7];
    unsigned ca = ctrl[2]; if (ca > CAND_CAP) ca = CAND_CAP;
    return (ctrl[3] == 0u) && (k >= cb) && (k - cb < ca);
}

// Block-wide exclusive scan over NT values (Hillis-Steele). Returns exclusive prefix.
template <int NT>
__device__ __forceinline__ unsigned block_exscan(unsigned val, unsigned* tmp) {
    const int t = threadIdx.x;
    tmp[t] = val;
    __syncthreads();
#pragma unroll
    for (int off = 1; off < NT; off <<= 1) {
        unsigned v = (t >= off) ? tmp[t - off] : 0u;
        __syncthreads();
        tmp[t] += v;
        __syncthreads();
    }
    return tmp[t] - val;
}

// Find bin b such that sum(bins[0..b)) <= k < sum(bins[0..b]). bins length = NT*C.
template <int NT, int C>
__device__ __forceinline__ void find_crossing(const unsigned* bins, unsigned k,
                                              unsigned* tmp, unsigned* res) {
    unsigned s = 0;
#pragma unroll
    for (int j = 0; j < C; ++j) s += bins[threadIdx.x * C + j];
    unsigned ex = block_exscan<NT>(s, tmp);
    if (k >= ex && k < ex + s) {  // exactly one thread
        unsigned cum = ex;
        int b = threadIdx.x * C;
        while (cum + bins[b] <= k) { cum += bins[b]; ++b; }
        res[0] = (unsigned)b;
        res[1] = k - cum;
    }
    __syncthreads();
}

// ---- Pass 1: count keys <= keyLo (register counter, no hot-loop atomics)
//      + compact window candidates (keyLo < key < keyHi) to candA. Streaming read. ----
__global__ __launch_bounds__(256) void pass1_kernel(
        const float4* __restrict__ x, int n4, unsigned* __restrict__ ctrl,
        unsigned* __restrict__ candA, unsigned keyLo, unsigned keyHi) {
    __shared__ unsigned cbuf[CBUF];
    __shared__ unsigned red[256];
    __shared__ unsigned ccnt, sbase, scnt;
    if (threadIdx.x == 0) ccnt = 0;
    __syncthreads();
    unsigned cnt = 0;
    const int stride = gridDim.x * blockDim.x;
    for (int i = blockIdx.x * blockDim.x + threadIdx.x; i < n4; i += stride) {
        float4 v = x[i];
        unsigned k0 = f2key(__float_as_uint(v.x));
        unsigned k1 = f2key(__float_as_uint(v.y));
        unsigned k2 = f2key(__float_as_uint(v.z));
        unsigned k3 = f2key(__float_as_uint(v.w));
        cnt += (unsigned)(k0 <= keyLo) + (unsigned)(k1 <= keyLo) +
               (unsigned)(k2 <= keyLo) + (unsigned)(k3 <= keyLo);
        if (k0 > keyLo && k0 < keyHi) { unsigned p = atomicAdd(&ccnt, 1u); if (p < CBUF) cbuf[p] = k0; }
        if (k1 > keyLo && k1 < keyHi) { unsigned p = atomicAdd(&ccnt, 1u); if (p < CBUF) cbuf[p] = k1; }
        if (k2 > keyLo && k2 < keyHi) { unsigned p = atomicAdd(&ccnt, 1u); if (p < CBUF) cbuf[p] = k2; }
        if (k3 > keyLo && k3 < keyHi) { unsigned p = atomicAdd(&ccnt, 1u); if (p < CBUF) cbuf[p] = k3; }
    }
    // block-reduce the below-count, one global atomic per block
    red[threadIdx.x] = cnt;
    __syncthreads();
#pragma unroll
    for (int off = 128; off > 0; off >>= 1) {
        if (threadIdx.x < off) red[threadIdx.x] += red[threadIdx.x + off];
        __syncthreads();
    }
    if (threadIdx.x == 0) atomicAdd(&ctrl[7], red[0]);
    // flush candidates
    if (threadIdx.x == 0) {
        unsigned c = ccnt;
        if (c > CBUF) { c = CBUF; atomicOr(&ctrl[3], 1u); }          // LDS buffer overflow
        unsigned base = atomicAdd(&ctrl[2], c);
        if (base + c > CAND_CAP) {                                    // global buffer overflow
            atomicOr(&ctrl[3], 1u);
            c = base < CAND_CAP ? CAND_CAP - base : 0;
        }
        sbase = base; scnt = c;
    }
    __syncthreads();
    for (unsigned i = threadIdx.x; i < scnt; i += 256) candA[sbase + i] = cbuf[i];
}

// ---- Fallback prepass: full 2048-bin histogram of top-11 key bits.
//      Early-out (launch-overhead only) when the window covers rank k. ----
__global__ __launch_bounds__(256) void fallback_hist_kernel(
        const float4* __restrict__ x, int n4, unsigned* __restrict__ ghist,
        const unsigned* __restrict__ ctrl, unsigned k) {
    if (is_covered(ctrl, k)) return;
    __shared__ unsigned h[4 * 2048];   // per-wave private histograms
    const int wave = threadIdx.x >> 6;
    unsigned* hw = &h[wave * 2048];
    for (int i = threadIdx.x; i < 4 * 2048; i += 256) h[i] = 0;
    __syncthreads();
    const int stride = gridDim.x * blockDim.x;
    for (int i = blockIdx.x * blockDim.x + threadIdx.x; i < n4; i += stride) {
        float4 v = x[i];
        atomicAdd(&hw[f2key(__float_as_uint(v.x)) >> 21], 1u);
        atomicAdd(&hw[f2key(__float_as_uint(v.y)) >> 21], 1u);
        atomicAdd(&hw[f2key(__float_as_uint(v.z)) >> 21], 1u);
        atomicAdd(&hw[f2key(__float_as_uint(v.w)) >> 21], 1u);
    }
    __syncthreads();
    for (int b = threadIdx.x; b < 2048; b += 256) {
        unsigned s = h[b] + h[2048 + b] + h[4096 + b] + h[6144 + b];
        if (s) atomicAdd(&ghist[b], s);
    }
}

// ---- Exact median, single launch (1024 threads).
//      Covered path (always taken on N(0,1)): rank (k - cntBelow) among candA via
//      linear-bin histogram + tiny exact rank-count. Reads candA straight from
//      L2/L3 (107 KB, just written) — no LDS staging pass.
//      Fallback path (never taken, correctness-only): find bucket from ghist,
//      then exact 3-level key-bit select via single-block passes over x. ----
__global__ __launch_bounds__(1024) void final_select_kernel(
        unsigned* __restrict__ ctrl, const unsigned* __restrict__ candA,
        float* __restrict__ medp, unsigned k, float W,
        const float4* __restrict__ x, int n4,
        const unsigned* __restrict__ ghist) {
    __shared__ unsigned cbin[CSEL];      // 16 KB chosen-bin compaction
    __shared__ unsigned h2[2048];
    __shared__ unsigned tmp[1024];
    __shared__ unsigned res[2];
    __shared__ unsigned csize;
    const int t = threadIdx.x;
    if (is_covered(ctrl, k)) {
        const unsigned M = ctrl[2];      // exact: no overflow on covered path
        const unsigned r = k - ctrl[7];
        if (t == 0) csize = 0;
        const float scale = 1024.0f / W;   // 2048 bins over (-W, W)
        // Level 0: linear-bin histogram over candA (M ~ 27k -> ~27 iters)
        for (unsigned i = t; i < 2048; i += 1024) h2[i] = 0;
        __syncthreads();
        for (unsigned i = t; i < M; i += 1024) atomicAdd(&h2[linbin(candA[i], W, scale)], 1u);
        __syncthreads();
        find_crossing<1024, 2>(h2, r, tmp, res);
        const unsigned b0 = res[0];
        const unsigned r0 = res[1];
        __syncthreads();
        // Compact chosen-bin members (~13 expected)
        for (unsigned i = t; i < M; i += 1024) {
            unsigned key = candA[i];
            if (linbin(key, W, scale) == b0) {
                unsigned p = atomicAdd(&csize, 1u);
                if (p < CSEL) cbin[p] = key;
            }
        }
        __syncthreads();
        const unsigned C = csize;
        if (C <= CSEL) {
            // Exact rank-count: key K is r0-th smallest iff #{<K} <= r0 < #{<=K}.
            for (unsigned i = t; i < C; i += 1024) {
                unsigned key = cbin[i];
                unsigned less = 0, eq = 0;
                for (unsigned j = 0; j < C; ++j) {
                    unsigned kj = cbin[j];   // broadcast read, conflict-free
                    less += (unsigned)(kj < key);
                    eq += (unsigned)(kj == key);
                }
                if (less <= r0 && r0 < less + eq) res[0] = key;
            }
            __syncthreads();
            if (t == 0) *medp = key2f(res[0]);
        } else {
            // Adversarial concentration inside one linear bin: exact 3-level
            // key-bit select over candA restricted to bin b0.
            for (unsigned i = t; i < 2048; i += 1024) h2[i] = 0;
            __syncthreads();
            for (unsigned i = t; i < M; i += 1024) {
                unsigned key = candA[i];
                if (linbin(key, W, scale) == b0) atomicAdd(&h2[key >> 21], 1u);
            }
            __syncthreads();
            find_crossing<1024, 2>(h2, r0, tmp, res);
            const unsigned b1 = res[0];
            const unsigned r1 = res[1];
            __syncthreads();
            for (unsigned i = t; i < 2048; i += 1024) h2[i] = 0;
            __syncthreads();
            for (unsigned i = t; i < M; i += 1024) {
                unsigned key = candA[i];
                if (linbin(key, W, scale) == b0 && (key >> 21) == b1)
                    atomicAdd(&h2[(key >> 10) & 0x7FFu], 1u);
            }
            __syncthreads();
            find_crossing<1024, 2>(h2, r1, tmp, res);
            const unsigned pref = (b1 << 11) | res[0];
            const unsigned r2 = res[1];
            __syncthreads();
            for (unsigned i = t; i < 1024; i += 1024) h2[i] = 0;
            __syncthreads();
            for (unsigned i = t; i < M; i += 1024) {
                unsigned key = candA[i];
                if (linbin(key, W, scale) == b0 && (key >> 10) == pref)
                    atomicAdd(&h2[key & 0x3FFu], 1u);
            }
            __syncthreads();
            find_crossing<1024, 1>(h2, r2, tmp, res);
            if (t == 0) *medp = key2f((pref << 10) | res[0]);
        }
    } else {
        // ---- Correctness-only fallback (slow: single-block passes over x). ----
        // Level 1: bucket from ghist (bits [31:21]).
        for (unsigned i = t; i < 2048; i += 1024) h2[i] = ghist[i];
        __syncthreads();
        find_crossing<1024, 2>(h2, k, tmp, res);
        const unsigned b1 = res[0];
        const unsigned r1 = res[1];
        __syncthreads();
        // Level 2: bits [20:10] among bucket-b1 keys (pass over x).
        for (unsigned i = t; i < 2048; i += 1024) h2[i] = 0;
        __syncthreads();
        for (int i = t; i < n4; i += 1024) {
            float4 v = x[i];
            unsigned ks[4] = { f2key(__float_as_uint(v.x)), f2key(__float_as_uint(v.y)),
                               f2key(__float_as_uint(v.z)), f2key(__float_as_uint(v.w)) };
#pragma unroll
            for (int j = 0; j < 4; ++j)
                if ((ks[j] >> 21) == b1) atomicAdd(&h2[(ks[j] >> 10) & 0x7FFu], 1u);
        }
        __syncthreads();
        find_crossing<1024, 2>(h2, r1, tmp, res);
        const unsigned pref = (b1 << 11) | res[0];
        const unsigned r2 = res[1];
        __syncthreads();
        // Level 3: bits [9:0] among pref keys (pass over x).
        for (unsigned i = t; i < 1024; i += 1024) h2[i] = 0;
        __syncthreads();
        for (int i = t; i < n4; i += 1024) {
            float4 v = x[i];
            unsigned ks[4] = { f2key(__float_as_uint(v.x)), f2key(__float_as_uint(v.y)),
                               f2key(__float_as_uint(v.z)), f2key(__float_as_uint(v.w)) };
#pragma unroll
            for (int j = 0; j < 4; ++j)
                if ((ks[j] >> 10) == pref) atomicAdd(&h2[ks[j] & 0x3FFu], 1u);
        }
        __syncthreads();
        find_crossing<1024, 1>(h2, r2, tmp, res);
        if (t == 0) *medp = key2f((pref << 10) | res[0]);
    }
}

// ---- Fused threshold + 7x7 maxpool + NMS: all-b128 LDS, bank-optimal strides ----
// (Horizontal-first separable max. Verified conflict-free: every wave b128 access
//  pattern hits each bank exactly 8 times. Vertical-first is structurally 4-way
//  conflicted — do not switch back. Regular stores — nt-store theory falsified
//  in round 2: reverting nt recovered ~0 µs.)
__global__ __launch_bounds__(256, 6) void nms_kernel(const float* __restrict__ x,
                                                     float* __restrict__ out,
                                                     const float* __restrict__ medp) {
    __shared__ __align__(16) float sin_[TILE_H * SIN_STR];  // 38x76 dwords = 11.5 KB
    __shared__ __align__(16) float shm[TILE_H * SHM_STR];   // 38x68 dwords = 10.3 KB
    const float med = *medp;
    const int tx0 = blockIdx.x * TX;
    const int ty0 = blockIdx.y * TY;
    const size_t ib = (size_t)blockIdx.z * (size_t)(IMG_H * IMG_W);
    const float* img = x + ib;
    float* oimg = out + ib;
    const bool colsafe = (tx0 >= 4) && (tx0 + 68 <= IMG_W);

    // Phase 1: load 38x72 halo tile as float4, threshold on the fly.
    for (int task = threadIdx.x; task < TILE_H * 18; task += 256) {
        int rr = task / 18;
        int c4 = task - rr * 18;
        int gy = ty0 + rr - HALO;
        int gx0 = tx0 - 4 + c4 * 4;
        float4 v;
        if ((unsigned)gy < (unsigned)IMG_H) {
            if (colsafe) {
                v = *(const float4*)(img + (size_t)gy * IMG_W + gx0);
                v.x = (v.x > med) ? v.x : 0.0f;
                v.y = (v.y > med) ? v.y : 0.0f;
                v.z = (v.z > med) ? v.z : 0.0f;
                v.w = (v.w > med) ? v.w : 0.0f;
            } else {
                float c[4];
#pragma unroll
                for (int j = 0; j < 4; ++j) {
                    int gx = gx0 + j;
                    if ((unsigned)gx < (unsigned)IMG_W) {
                        float xv = img[(size_t)gy * IMG_W + gx];
                        c[j] = (xv > med) ? xv : 0.0f;
                    } else c[j] = -INFINITY;
                }
                v = make_float4(c[0], c[1], c[2], c[3]);
            }
        } else {
            v = make_float4(-INFINITY, -INFINITY, -INFINITY, -INFINITY);
        }
        *(float4*)&sin_[rr * SIN_STR + c4 * 4] = v;
    }
    __syncthreads();

    // Phase 2: horizontal 7-tap max. 38 rows x 4 segments of 16 outputs.
    for (int task = threadIdx.x; task < TILE_H * 4; task += 256) {
        int rr = task >> 2;
        int s = task & 3;
        int c0 = s * 16;
        const float* p = &sin_[rr * SIN_STR + c0];
        float v[24];
#pragma unroll
        for (int b = 0; b < 6; ++b) {
            float4 q = *(const float4*)(p + 4 * b);
            v[4 * b] = q.x; v[4 * b + 1] = q.y; v[4 * b + 2] = q.z; v[4 * b + 3] = q.w;
        }
        float m2[22];
#pragma unroll
        for (int j = 1; j <= 21; ++j) m2[j] = fmaxf(v[j], v[j + 1]);
        float m4[20];
#pragma unroll
        for (int j = 1; j <= 19; ++j) m4[j] = fmaxf(m2[j], m2[j + 2]);
        float o[16];
#pragma unroll
        for (int j = 0; j < 16; ++j) o[j] = fmaxf(m4[j + 1], m4[j + 4]);  // max sin[j+1..j+7]
        float* q = &shm[rr * SHM_STR + c0];
#pragma unroll
        for (int b = 0; b < 4; ++b)
            *(float4*)(q + 4 * b) = make_float4(o[4 * b], o[4 * b + 1], o[4 * b + 2], o[4 * b + 3]);
    }
    __syncthreads();

    // Phase 3: vertical 7-tap max on float4 columns + NMS compare + float4 stores.
    {
        const int col4 = threadIdx.x & 15;
        const int r0 = (threadIdx.x >> 4) * 2;
        float4 v[8];
#pragma unroll
        for (int j = 0; j < 8; ++j) v[j] = *(const float4*)&shm[(r0 + j) * SHM_STR + col4 * 4];
        float4 m2[7];
#pragma unroll
        for (int j = 0; j < 7; ++j) m2[j] = fmax4(v[j], v[j + 1]);
        float4 m4[5];
#pragma unroll
        for (int j = 0; j < 5; ++j) m4[j] = fmax4(m2[j], m2[j + 2]);
        float4 ma = fmax4(m4[0], m4[3]);  // rows r0..r0+6   -> out row r0
        float4 mb = fmax4(m4[1], m4[4]);  // rows r0+1..r0+7 -> out row r0+1
        float4 ta = *(const float4*)&sin_[(r0 + HALO) * SIN_STR + col4 * 4 + 4];
        float4 tb = *(const float4*)&sin_[(r0 + 1 + HALO) * SIN_STR + col4 * 4 + 4];
        float4 oa = make_float4((ta.x == ma.x) ? ta.x : 0.0f, (ta.y == ma.y) ? ta.y : 0.0f,
                                (ta.z == ma.z) ? ta.z : 0.0f, (ta.w == ma.w) ? ta.w : 0.0f);
        float4 ob = make_float4((tb.x == mb.x) ? tb.x : 0.0f, (tb.y == mb.y) ? tb.y : 0.0f,
                                (tb.z == mb.z) ? tb.z : 0.0f, (tb.w == mb.w) ? tb.w : 0.0f);
        *(float4*)(oimg + (size_t)(ty0 + r0) * IMG_W + tx0 + col4 * 4) = oa;
        *(float4*)(oimg + (size_t)(ty0 + r0 + 1) * IMG_W + tx0 + col4 * 4) = ob;
    }
}

extern "C" void kernel_launch(void* const* d_in, const int* in_sizes, int n_in,
                              void* d_out, int out_size, void* d_ws, size_t ws_size,
                              hipStream_t stream) {
    const float* x = (const float*)d_in[0];
    float* out = (float*)d_out;
    const int n = in_sizes[0];                   // 8*2048*2048
    const int n4 = n / 4;
    const unsigned k = (unsigned)((n - 1) / 2);  // lower-median rank (0-indexed)

    unsigned char* ws = (unsigned char*)d_ws;
    unsigned* ghist = (unsigned*)ws;               // 2048 u32
    unsigned* ctrl = (unsigned*)(ws + 2048 * 4);   // 16 u32, see layout comment
    float* medp = (float*)(ctrl + 8);
    unsigned* candA = (unsigned*)(ws + 2048 * 4 + 64);
    const size_t reserved = 2048 * 4 + 64;

    // ws is re-poisoned to 0xAA before every timed launch: zero hist + control words.
    hipMemsetAsync(d_ws, 0, reserved, stream);

    // Window around the expected median of ~N(0,1): |x| < 0.001 (~4.6 sigma of the
    // sample-median distribution at n=33.5M; P(not covered) ~ 4e-6). Coverage is
    // verified EXACTLY in key space via countBelow/cntA; the fallback path
    // (fallback_hist + final_select's slow branch) handles arbitrary inputs.
    const float W = 0.001f;
    const unsigned keyLo = f2key_host(-W);
    const unsigned keyHi = f2key_host(W);

    pass1_kernel<<<1024, 256, 0, stream>>>((const float4*)x, n4, ctrl, candA, keyLo, keyHi);
    fallback_hist_kernel<<<1024, 256, 0, stream>>>((const float4*)x, n4, ghist, ctrl, k);
    final_select_kernel<<<1, 1024, 0, stream>>>(ctrl, candA, medp, k, W,
                                                (const float4*)x, n4, ghist);

    dim3 grid(IMG_W / TX, IMG_H / TY, n / (IMG_H * IMG_W));
    nms_kernel<<<grid, 256, 0, stream>>>(x, out, medp);
}

// Round 4
// 312.698 us; speedup vs baseline: 1.0453x; 1.0001x over previous
//
#include <hip/hip_runtime.h>
#include <math.h>

#define IMG_H 2048
#define IMG_W 2048
#define TX 64
#define TY 32
#define HALO 3
#define TILE_H (TY + 2 * HALO)      // 38 halo rows
#define SIN_STR 76                  // dwords; 72 cols loaded + pad; verified conflict-free for b128
#define SHM_STR 68                  // dwords; 64 cols + pad; verified conflict-free for b128
#define CAND_CAP (1u << 20)
#define CBUF 1024
#define CSEL 4096                   // bin-compaction capacity (16 KB); expected ~13 members/bin

__device__ __forceinline__ float4 fmax4(float4 a, float4 b) {
    return make_float4(fmaxf(a.x, b.x), fmaxf(a.y, b.y), fmaxf(a.z, b.z), fmaxf(a.w, b.w));
}

// Order-preserving float->uint key: ascending float order == ascending uint order.
__device__ __forceinline__ unsigned f2key(unsigned u) {
    unsigned mask = (unsigned)(((int)u >> 31)) | 0x80000000u;
    return u ^ mask;
}
static inline unsigned f2key_host(float f) {
    union { float f; unsigned u; } c; c.f = f;
    unsigned mask = (unsigned)(((int)c.u >> 31)) | 0x80000000u;
    return c.u ^ mask;
}

// key -> float (inverse of f2key)
__device__ __forceinline__ float key2f(unsigned key) {
    unsigned u = (key & 0x80000000u) ? (key ^ 0x80000000u) : ~key;
    return __uint_as_float(u);
}

// Linear 2048-bin quantization of a window candidate (float strictly in (-W, W)).
// Monotone in key order; near-uniform occupancy for locally-flat densities ->
// no same-address LDS-atomic serialization (key-exponent bits would concentrate
// ~27k candidates into ~16 bins).
__device__ __forceinline__ unsigned linbin(unsigned key, float W, float scale) {
    float p = (key2f(key) + W) * scale;
    int b = (int)p;
    b = b < 0 ? 0 : (b > 2047 ? 2047 : b);
    return (unsigned)b;
}

// ctrl layout (16 u32 at ws base, zeroed before launch):
// [2]=cntA(window cands) [3]=ovf [7]=cntBelow ; medp at ctrl+8.
__device__ __forceinline__ bool is_covered(const unsigned* __restrict__ ctrl, unsigned k) {
    unsigned cb = ctrl[7];
    unsigned ca = ctrl[2]; if (ca > CAND_CAP) ca = CAND_CAP;
    return (ctrl[3] == 0u) && (k >= cb) && (k - cb < ca);
}

// Block-wide exclusive scan over NT values (Hillis-Steele). Returns exclusive prefix.
template <int NT>
__device__ __forceinline__ unsigned block_exscan(unsigned val, unsigned* tmp) {
    const int t = threadIdx.x;
    tmp[t] = val;
    __syncthreads();
#pragma unroll
    for (int off = 1; off < NT; off <<= 1) {
        unsigned v = (t >= off) ? tmp[t - off] : 0u;
        __syncthreads();
        tmp[t] += v;
        __syncthreads();
    }
    return tmp[t] - val;
}

// Find bin b such that sum(bins[0..b)) <= k < sum(bins[0..b]). bins length = NT*C.
template <int NT, int C>
__device__ __forceinline__ void find_crossing(const unsigned* bins, unsigned k,
                                              unsigned* tmp, unsigned* res) {
    unsigned s = 0;
#pragma unroll
    for (int j = 0; j < C; ++j) s += bins[threadIdx.x * C + j];
    unsigned ex = block_exscan<NT>(s, tmp);
    if (k >= ex && k < ex + s) {  // exactly one thread
        unsigned cum = ex;
        int b = threadIdx.x * C;
        while (cum + bins[b] <= k) { cum += bins[b]; ++b; }
        res[0] = (unsigned)b;
        res[1] = k - cum;
    }
    __syncthreads();
}

// ---- Pass 1: count keys <= keyLo (register counter, no hot-loop atomics)
//      + compact window candidates (keyLo < key < keyHi) to candA. Streaming read. ----
__global__ __launch_bounds__(256) void pass1_kernel(
        const float4* __restrict__ x, int n4, unsigned* __restrict__ ctrl,
        unsigned* __restrict__ candA, unsigned keyLo, unsigned keyHi) {
    __shared__ unsigned cbuf[CBUF];
    __shared__ unsigned red[256];
    __shared__ unsigned ccnt, sbase, scnt;
    if (threadIdx.x == 0) ccnt = 0;
    __syncthreads();
    unsigned cnt = 0;
    const int stride = gridDim.x * blockDim.x;
    for (int i = blockIdx.x * blockDim.x + threadIdx.x; i < n4; i += stride) {
        float4 v = x[i];
        unsigned k0 = f2key(__float_as_uint(v.x));
        unsigned k1 = f2key(__float_as_uint(v.y));
        unsigned k2 = f2key(__float_as_uint(v.z));
        unsigned k3 = f2key(__float_as_uint(v.w));
        cnt += (unsigned)(k0 <= keyLo) + (unsigned)(k1 <= keyLo) +
               (unsigned)(k2 <= keyLo) + (unsigned)(k3 <= keyLo);
        if (k0 > keyLo && k0 < keyHi) { unsigned p = atomicAdd(&ccnt, 1u); if (p < CBUF) cbuf[p] = k0; }
        if (k1 > keyLo && k1 < keyHi) { unsigned p = atomicAdd(&ccnt, 1u); if (p < CBUF) cbuf[p] = k1; }
        if (k2 > keyLo && k2 < keyHi) { unsigned p = atomicAdd(&ccnt, 1u); if (p < CBUF) cbuf[p] = k2; }
        if (k3 > keyLo && k3 < keyHi) { unsigned p = atomicAdd(&ccnt, 1u); if (p < CBUF) cbuf[p] = k3; }
    }
    // block-reduce the below-count, one global atomic per block
    red[threadIdx.x] = cnt;
    __syncthreads();
#pragma unroll
    for (int off = 128; off > 0; off >>= 1) {
        if (threadIdx.x < off) red[threadIdx.x] += red[threadIdx.x + off];
        __syncthreads();
    }
    if (threadIdx.x == 0) atomicAdd(&ctrl[7], red[0]);
    // flush candidates
    if (threadIdx.x == 0) {
        unsigned c = ccnt;
        if (c > CBUF) { c = CBUF; atomicOr(&ctrl[3], 1u); }          // LDS buffer overflow
        unsigned base = atomicAdd(&ctrl[2], c);
        if (base + c > CAND_CAP) {                                    // global buffer overflow
            atomicOr(&ctrl[3], 1u);
            c = base < CAND_CAP ? CAND_CAP - base : 0;
        }
        sbase = base; scnt = c;
    }
    __syncthreads();
    for (unsigned i = threadIdx.x; i < scnt; i += 256) candA[sbase + i] = cbuf[i];
}

// ---- Exact median, single launch (1024 threads).
//      Covered path (always taken on N(0,1)): rank (k - cntBelow) among candA via
//      linear-bin histogram + tiny exact rank-count. Reads candA straight from
//      L2/L3 (107 KB, just written).
//      Fallback path (never taken on this data, correctness-only): exact 4-level
//      key-bit select via single-block passes over x — slow but exact; coverage
//      failure probability ~4e-6 and is detected EXACTLY, so the fallback only
//      needs correctness, not speed. ----
__global__ __launch_bounds__(1024) void final_select_kernel(
        unsigned* __restrict__ ctrl, const unsigned* __restrict__ candA,
        float* __restrict__ medp, unsigned k, float W,
        const float4* __restrict__ x, int n4) {
    __shared__ unsigned cbin[CSEL];      // 16 KB chosen-bin compaction
    __shared__ unsigned h2[2048];
    __shared__ unsigned tmp[1024];
    __shared__ unsigned res[2];
    __shared__ unsigned csize;
    const int t = threadIdx.x;
    if (is_covered(ctrl, k)) {
        const unsigned M = ctrl[2];      // exact: no overflow on covered path
        const unsigned r = k - ctrl[7];
        if (t == 0) csize = 0;
        const float scale = 1024.0f / W;   // 2048 bins over (-W, W)
        // Level 0: linear-bin histogram over candA (M ~ 27k -> ~27 iters)
        for (unsigned i = t; i < 2048; i += 1024) h2[i] = 0;
        __syncthreads();
        for (unsigned i = t; i < M; i += 1024) atomicAdd(&h2[linbin(candA[i], W, scale)], 1u);
        __syncthreads();
        find_crossing<1024, 2>(h2, r, tmp, res);
        const unsigned b0 = res[0];
        const unsigned r0 = res[1];
        __syncthreads();
        // Compact chosen-bin members (~13 expected)
        for (unsigned i = t; i < M; i += 1024) {
            unsigned key = candA[i];
            if (linbin(key, W, scale) == b0) {
                unsigned p = atomicAdd(&csize, 1u);
                if (p < CSEL) cbin[p] = key;
            }
        }
        __syncthreads();
        const unsigned C = csize;
        if (C <= CSEL) {
            // Exact rank-count: key K is r0-th smallest iff #{<K} <= r0 < #{<=K}.
            for (unsigned i = t; i < C; i += 1024) {
                unsigned key = cbin[i];
                unsigned less = 0, eq = 0;
                for (unsigned j = 0; j < C; ++j) {
                    unsigned kj = cbin[j];   // broadcast read, conflict-free
                    less += (unsigned)(kj < key);
                    eq += (unsigned)(kj == key);
                }
                if (less <= r0 && r0 < less + eq) res[0] = key;
            }
            __syncthreads();
            if (t == 0) *medp = key2f(res[0]);
        } else {
            // Adversarial concentration inside one linear bin: exact 3-level
            // key-bit select over candA restricted to bin b0.
            for (unsigned i = t; i < 2048; i += 1024) h2[i] = 0;
            __syncthreads();
            for (unsigned i = t; i < M; i += 1024) {
                unsigned key = candA[i];
                if (linbin(key, W, scale) == b0) atomicAdd(&h2[key >> 21], 1u);
            }
            __syncthreads();
            find_crossing<1024, 2>(h2, r0, tmp, res);
            const unsigned b1 = res[0];
            const unsigned r1 = res[1];
            __syncthreads();
            for (unsigned i = t; i < 2048; i += 1024) h2[i] = 0;
            __syncthreads();
            for (unsigned i = t; i < M; i += 1024) {
                unsigned key = candA[i];
                if (linbin(key, W, scale) == b0 && (key >> 21) == b1)
                    atomicAdd(&h2[(key >> 10) & 0x7FFu], 1u);
            }
            __syncthreads();
            find_crossing<1024, 2>(h2, r1, tmp, res);
            const unsigned pref = (b1 << 11) | res[0];
            const unsigned r2 = res[1];
            __syncthreads();
            for (unsigned i = t; i < 1024; i += 1024) h2[i] = 0;
            __syncthreads();
            for (unsigned i = t; i < M; i += 1024) {
                unsigned key = candA[i];
                if (linbin(key, W, scale) == b0 && (key >> 10) == pref)
                    atomicAdd(&h2[key & 0x3FFu], 1u);
            }
            __syncthreads();
            find_crossing<1024, 1>(h2, r2, tmp, res);
            if (t == 0) *medp = key2f((pref << 10) | res[0]);
        }
    } else {
        // ---- Correctness-only fallback: 4-level select, single-block passes over x. ----
        // Level 1: bits [31:21] histogram over all of x.
        for (unsigned i = t; i < 2048; i += 1024) h2[i] = 0;
        __syncthreads();
        for (int i = t; i < n4; i += 1024) {
            float4 v = x[i];
            atomicAdd(&h2[f2key(__float_as_uint(v.x)) >> 21], 1u);
            atomicAdd(&h2[f2key(__float_as_uint(v.y)) >> 21], 1u);
            atomicAdd(&h2[f2key(__float_as_uint(v.z)) >> 21], 1u);
            atomicAdd(&h2[f2key(__float_as_uint(v.w)) >> 21], 1u);
        }
        __syncthreads();
        find_crossing<1024, 2>(h2, k, tmp, res);
        const unsigned b1 = res[0];
        const unsigned r1 = res[1];
        __syncthreads();
        // Level 2: bits [20:10] among bucket-b1 keys (pass over x).
        for (unsigned i = t; i < 2048; i += 1024) h2[i] = 0;
        __syncthreads();
        for (int i = t; i < n4; i += 1024) {
            float4 v = x[i];
            unsigned ks[4] = { f2key(__float_as_uint(v.x)), f2key(__float_as_uint(v.y)),
                               f2key(__float_as_uint(v.z)), f2key(__float_as_uint(v.w)) };
#pragma unroll
            for (int j = 0; j < 4; ++j)
                if ((ks[j] >> 21) == b1) atomicAdd(&h2[(ks[j] >> 10) & 0x7FFu], 1u);
        }
        __syncthreads();
        find_crossing<1024, 2>(h2, r1, tmp, res);
        const unsigned pref = (b1 << 11) | res[0];
        const unsigned r2 = res[1];
        __syncthreads();
        // Level 3: bits [9:0] among pref keys (pass over x).
        for (unsigned i = t; i < 1024; i += 1024) h2[i] = 0;
        __syncthreads();
        for (int i = t; i < n4; i += 1024) {
            float4 v = x[i];
            unsigned ks[4] = { f2key(__float_as_uint(v.x)), f2key(__float_as_uint(v.y)),
                               f2key(__float_as_uint(v.z)), f2key(__float_as_uint(v.w)) };
#pragma unroll
            for (int j = 0; j < 4; ++j)
                if ((ks[j] >> 10) == pref) atomicAdd(&h2[ks[j] & 0x3FFu], 1u);
        }
        __syncthreads();
        find_crossing<1024, 1>(h2, r2, tmp, res);
        if (t == 0) *medp = key2f((pref << 10) | res[0]);
    }
}

// ---- Fused threshold + 7x7 maxpool + NMS: all-b128 LDS, bank-optimal strides ----
// (Horizontal-first separable max. Verified conflict-free: every wave b128 access
//  pattern hits each bank exactly 8 times. Vertical-first is structurally 4-way
//  conflicted — do not switch back. Regular stores — nt-store theory falsified
//  in round 2: reverting nt recovered ~0 µs.)
__global__ __launch_bounds__(256, 6) void nms_kernel(const float* __restrict__ x,
                                                     float* __restrict__ out,
                                                     const float* __restrict__ medp) {
    __shared__ __align__(16) float sin_[TILE_H * SIN_STR];  // 38x76 dwords = 11.5 KB
    __shared__ __align__(16) float shm[TILE_H * SHM_STR];   // 38x68 dwords = 10.3 KB
    const float med = *medp;
    const int tx0 = blockIdx.x * TX;
    const int ty0 = blockIdx.y * TY;
    const size_t ib = (size_t)blockIdx.z * (size_t)(IMG_H * IMG_W);
    const float* img = x + ib;
    float* oimg = out + ib;
    const bool colsafe = (tx0 >= 4) && (tx0 + 68 <= IMG_W);

    // Phase 1: load 38x72 halo tile as float4, threshold on the fly.
    for (int task = threadIdx.x; task < TILE_H * 18; task += 256) {
        int rr = task / 18;
        int c4 = task - rr * 18;
        int gy = ty0 + rr - HALO;
        int gx0 = tx0 - 4 + c4 * 4;
        float4 v;
        if ((unsigned)gy < (unsigned)IMG_H) {
            if (colsafe) {
                v = *(const float4*)(img + (size_t)gy * IMG_W + gx0);
                v.x = (v.x > med) ? v.x : 0.0f;
                v.y = (v.y > med) ? v.y : 0.0f;
                v.z = (v.z > med) ? v.z : 0.0f;
                v.w = (v.w > med) ? v.w : 0.0f;
            } else {
                float c[4];
#pragma unroll
                for (int j = 0; j < 4; ++j) {
                    int gx = gx0 + j;
                    if ((unsigned)gx < (unsigned)IMG_W) {
                        float xv = img[(size_t)gy * IMG_W + gx];
                        c[j] = (xv > med) ? xv : 0.0f;
                    } else c[j] = -INFINITY;
                }
                v = make_float4(c[0], c[1], c[2], c[3]);
            }
        } else {
            v = make_float4(-INFINITY, -INFINITY, -INFINITY, -INFINITY);
        }
        *(float4*)&sin_[rr * SIN_STR + c4 * 4] = v;
    }
    __syncthreads();

    // Phase 2: horizontal 7-tap max. 38 rows x 4 segments of 16 outputs.
    for (int task = threadIdx.x; task < TILE_H * 4; task += 256) {
        int rr = task >> 2;
        int s = task & 3;
        int c0 = s * 16;
        const float* p = &sin_[rr * SIN_STR + c0];
        float v[24];
#pragma unroll
        for (int b = 0; b < 6; ++b) {
            float4 q = *(const float4*)(p + 4 * b);
            v[4 * b] = q.x; v[4 * b + 1] = q.y; v[4 * b + 2] = q.z; v[4 * b + 3] = q.w;
        }
        float m2[22];
#pragma unroll
        for (int j = 1; j <= 21; ++j) m2[j] = fmaxf(v[j], v[j + 1]);
        float m4[20];
#pragma unroll
        for (int j = 1; j <= 19; ++j) m4[j] = fmaxf(m2[j], m2[j + 2]);
        float o[16];
#pragma unroll
        for (int j = 0; j < 16; ++j) o[j] = fmaxf(m4[j + 1], m4[j + 4]);  // max sin[j+1..j+7]
        float* q = &shm[rr * SHM_STR + c0];
#pragma unroll
        for (int b = 0; b < 4; ++b)
            *(float4*)(q + 4 * b) = make_float4(o[4 * b], o[4 * b + 1], o[4 * b + 2], o[4 * b + 3]);
    }
    __syncthreads();

    // Phase 3: vertical 7-tap max on float4 columns + NMS compare + float4 stores.
    {
        const int col4 = threadIdx.x & 15;
        const int r0 = (threadIdx.x >> 4) * 2;
        float4 v[8];
#pragma unroll
        for (int j = 0; j < 8; ++j) v[j] = *(const float4*)&shm[(r0 + j) * SHM_STR + col4 * 4];
        float4 m2[7];
#pragma unroll
        for (int j = 0; j < 7; ++j) m2[j] = fmax4(v[j], v[j + 1]);
        float4 m4[5];
#pragma unroll
        for (int j = 0; j < 5; ++j) m4[j] = fmax4(m2[j], m2[j + 2]);
        float4 ma = fmax4(m4[0], m4[3]);  // rows r0..r0+6   -> out row r0
        float4 mb = fmax4(m4[1], m4[4]);  // rows r0+1..r0+7 -> out row r0+1
        float4 ta = *(const float4*)&sin_[(r0 + HALO) * SIN_STR + col4 * 4 + 4];
        float4 tb = *(const float4*)&sin_[(r0 + 1 + HALO) * SIN_STR + col4 * 4 + 4];
        float4 oa = make_float4((ta.x == ma.x) ? ta.x : 0.0f, (ta.y == ma.y) ? ta.y : 0.0f,
                                (ta.z == ma.z) ? ta.z : 0.0f, (ta.w == ma.w) ? ta.w : 0.0f);
        float4 ob = make_float4((tb.x == mb.x) ? tb.x : 0.0f, (tb.y == mb.y) ? tb.y : 0.0f,
                                (tb.z == mb.z) ? tb.z : 0.0f, (tb.w == mb.w) ? tb.w : 0.0f);
        *(float4*)(oimg + (size_t)(ty0 + r0) * IMG_W + tx0 + col4 * 4) = oa;
        *(float4*)(oimg + (size_t)(ty0 + r0 + 1) * IMG_W + tx0 + col4 * 4) = ob;
    }
}

extern "C" void kernel_launch(void* const* d_in, const int* in_sizes, int n_in,
                              void* d_out, int out_size, void* d_ws, size_t ws_size,
                              hipStream_t stream) {
    const float* x = (const float*)d_in[0];
    float* out = (float*)d_out;
    const int n = in_sizes[0];                   // 8*2048*2048
    const int n4 = n / 4;
    const unsigned k = (unsigned)((n - 1) / 2);  // lower-median rank (0-indexed)

    unsigned char* ws = (unsigned char*)d_ws;
    unsigned* ctrl = (unsigned*)ws;                // 16 u32, see layout comment
    float* medp = (float*)(ctrl + 8);
    unsigned* candA = (unsigned*)(ws + 64);
    const size_t reserved = 64;

    // ws is re-poisoned to 0xAA before every timed launch: zero the control words.
    hipMemsetAsync(d_ws, 0, reserved, stream);

    // Window around the expected median of ~N(0,1): |x| < 0.001 (~4.6 sigma of the
    // sample-median distribution at n=33.5M; P(not covered) ~ 4e-6). Coverage is
    // verified EXACTLY in key space via countBelow/cntA; final_select's fallback
    // branch (4-level single-block select over x) handles arbitrary inputs.
    const float W = 0.001f;
    const unsigned keyLo = f2key_host(-W);
    const unsigned keyHi = f2key_host(W);

    pass1_kernel<<<1024, 256, 0, stream>>>((const float4*)x, n4, ctrl, candA, keyLo, keyHi);
    final_select_kernel<<<1, 1024, 0, stream>>>(ctrl, candA, medp, k, W,
                                                (const float4*)x, n4);

    dim3 grid(IMG_W / TX, IMG_H / TY, n / (IMG_H * IMG_W));
    nms_kernel<<<grid, 256, 0, stream>>>(x, out, medp);
}